// Round 8
// baseline (684.771 us; speedup 1.0000x reference)
//
#include <hip/hip_runtime.h>
#include <math.h>

typedef short bf16x8 __attribute__((ext_vector_type(8)));
typedef float f32x4 __attribute__((ext_vector_type(4)));
typedef float f32x2 __attribute__((ext_vector_type(2)));

__device__ __forceinline__ unsigned short cvt_bf16(float f) {
    unsigned u = __float_as_uint(f);
    u += 0x7fffu + ((u >> 16) & 1);        // round-to-nearest-even
    return (unsigned short)(u >> 16);
}
__device__ __forceinline__ float cvt_f32(unsigned short b) {
    return __uint_as_float(((unsigned)b) << 16);
}
// bf16 pair (packed in one u32) -> 2 floats in 2 VALU ops
__device__ __forceinline__ f32x2 bf16pair(unsigned u) {
    f32x2 r;
    r.x = __uint_as_float(u << 16);
    r.y = __uint_as_float(u & 0xffff0000u);
    return r;
}

// ---------- compose relation weights, store TRANSPOSED bf16 [c][i] ----------
// k' = x @ (Wk . blockdiag(att)) * pri/4 ; v' = x @ (Wv . blockdiag(msg))
__global__ void compose_kernel(const float* __restrict__ Wk, const float* __restrict__ bk,
                               const float* __restrict__ Wv, const float* __restrict__ bv,
                               const float* __restrict__ att, const float* __restrict__ msg,
                               const float* __restrict__ pri,
                               unsigned short* __restrict__ WkT, unsigned short* __restrict__ WvT,
                               float* __restrict__ bkC, float* __restrict__ bvC) {
    int tid = blockIdx.x * blockDim.x + threadIdx.x;
    if (tid >= 3 * 16384) return;
    int r = tid / 16384;
    int rem = tid & 16383;
    int c = rem >> 7;       // output dim (row of W^T)
    int i = rem & 127;      // input dim
    int h = c >> 4, e = c & 15;
    int wsel = (r == 1) ? 1 : 0;
    float p = pri[r * 8 + h] * 0.25f;   // 1/sqrt(16)

    const float* wkrow = Wk + wsel * 16384 + i * 128 + h * 16;
    const float* wvrow = Wv + wsel * 16384 + i * 128 + h * 16;
    const float* attc = att + ((r * 8 + h) * 16) * 16 + e;
    const float* msgc = msg + ((r * 8 + h) * 16) * 16 + e;
    float aK = 0.f, aV = 0.f;
#pragma unroll
    for (int d = 0; d < 16; ++d) {
        aK += wkrow[d] * attc[d * 16];
        aV += wvrow[d] * msgc[d * 16];
    }
    WkT[r * 16384 + c * 128 + i] = cvt_bf16(aK * p);
    WvT[r * 16384 + c * 128 + i] = cvt_bf16(aV);
    if (i == 0) {
        const float* bkr = bk + wsel * 128 + h * 16;
        const float* bvr = bv + wsel * 128 + h * 16;
        float bK = 0.f, bV = 0.f;
#pragma unroll
        for (int d = 0; d < 16; ++d) {
            bK += bkr[d] * attc[d * 16];
            bV += bvr[d] * msgc[d * 16];
        }
        bkC[r * 128 + c] = bK * p;
        bvC[r * 128 + c] = bV;
    }
}

// ---------- transpose+cast 4 128x128 f32 matrices (Wq[0],Wq[1],Wa[0],Wa[1]) ----------
__global__ void tcast4_kernel(const float* __restrict__ Wq, const float* __restrict__ Wa,
                              unsigned short* __restrict__ WqT, unsigned short* __restrict__ WaT) {
    int m = blockIdx.y;
    const float* src = (m < 2) ? Wq + m * 16384 : Wa + (m - 2) * 16384;
    unsigned short* dst = (m < 2) ? WqT + m * 16384 : WaT + (m - 2) * 16384;
    int tid = blockIdx.x * 256 + threadIdx.x;   // 16384 per matrix
    int c = tid >> 7, i = tid & 127;
    dst[tid] = cvt_bf16(src[i * 128 + c]);      // dst[c][i] = src[i][c]
}

// ---------- merged multi-output MFMA projection over BOTH node types ----------
// X is f32 (cast fused into LDS staging). Blocks [0,gA): X=h_a, outputs 0..4 ;
// blocks [gA,2gA): X=h_b, outputs 5..7.
struct OutSpec { const unsigned short* Wt; const float* bias; unsigned short* out; };
struct OutSpecs8 { OutSpec o[8]; };

#define LPAD 136   // 128 + 8 bf16 pad: row stride 272 B -> bank step 4, 2-way (free)

__global__ __launch_bounds__(256) void mfma_proj2_kernel(const float* __restrict__ Xa,
                                                         const float* __restrict__ Xb,
                                                         int nrows, OutSpecs8 specs, int gA) {
    __shared__ unsigned short Xs[128 * LPAD];
    __shared__ unsigned short Ws[128 * LPAD];
    __shared__ float bs[128];
    int tid = threadIdx.x;
    int aSide = blockIdx.x < gA;
    const float* X = aSide ? Xa : Xb;
    int obase = aSide ? 0 : 5;
    int nout = aSide ? 5 : 3;
    int n0 = (aSide ? blockIdx.x : blockIdx.x - gA) * 128;
    int rows_in = nrows - n0; if (rows_in > 128) rows_in = 128;

    {   // stage X tile from f32, converting to bf16 (row-clamped for partial block)
        int rowb = tid >> 4, seg = tid & 15;
#pragma unroll
        for (int p = 0; p < 8; ++p) {
            int row = p * 16 + rowb;
            int rowg = row < rows_in ? row : rows_in - 1;
            const float* src = X + ((size_t)(n0 + rowg)) * 128 + seg * 8;
            float4 f0 = ((const float4*)src)[0];
            float4 f1 = ((const float4*)src)[1];
            ushort4 o0, o1;
            o0.x = cvt_bf16(f0.x); o0.y = cvt_bf16(f0.y); o0.z = cvt_bf16(f0.z); o0.w = cvt_bf16(f0.w);
            o1.x = cvt_bf16(f1.x); o1.y = cvt_bf16(f1.y); o1.z = cvt_bf16(f1.z); o1.w = cvt_bf16(f1.w);
            *(ushort4*)&Xs[row * LPAD + seg * 8] = o0;
            *(ushort4*)&Xs[row * LPAD + seg * 8 + 4] = o1;
        }
    }

    int wave = tid >> 6, lane = tid & 63;
    int l15 = lane & 15, quad = lane >> 4;

    for (int oo = 0; oo < nout; ++oo) {
        const unsigned short* Wt = specs.o[obase + oo].Wt;
        const float* bias = specs.o[obase + oo].bias;
        unsigned short* out = specs.o[obase + oo].out;
        {   // stage W^T
            int rowb = tid >> 4, seg = tid & 15;
#pragma unroll
            for (int p = 0; p < 8; ++p) {
                int row = p * 16 + rowb;
                uint4 d = *(const uint4*)(Wt + (size_t)row * 128 + seg * 8);
                *(uint4*)&Ws[row * LPAD + seg * 8] = d;
            }
            if (tid < 128) bs[tid] = bias[tid];
        }
        __syncthreads();

        f32x4 acc[2][8];
#pragma unroll
        for (int mi = 0; mi < 2; ++mi)
#pragma unroll
            for (int nt = 0; nt < 8; ++nt) acc[mi][nt] = (f32x4){0.f, 0.f, 0.f, 0.f};

#pragma unroll
        for (int ks = 0; ks < 4; ++ks) {
            bf16x8 afr[2];
            afr[0] = *(const bf16x8*)&Xs[(wave * 32 + l15) * LPAD + ks * 32 + quad * 8];
            afr[1] = *(const bf16x8*)&Xs[(wave * 32 + 16 + l15) * LPAD + ks * 32 + quad * 8];
#pragma unroll
            for (int nt = 0; nt < 8; ++nt) {
                bf16x8 bfr = *(const bf16x8*)&Ws[(nt * 16 + l15) * LPAD + ks * 32 + quad * 8];
                acc[0][nt] = __builtin_amdgcn_mfma_f32_16x16x32_bf16(afr[0], bfr, acc[0][nt], 0, 0, 0);
                acc[1][nt] = __builtin_amdgcn_mfma_f32_16x16x32_bf16(afr[1], bfr, acc[1][nt], 0, 0, 0);
            }
        }

#pragma unroll
        for (int mi = 0; mi < 2; ++mi) {
            int rowbase = wave * 32 + mi * 16 + quad * 4;
#pragma unroll
            for (int r = 0; r < 4; ++r) {
                int row = rowbase + r;
                if (row < rows_in) {
#pragma unroll
                    for (int nt = 0; nt < 8; ++nt) {
                        int col = nt * 16 + l15;
                        out[(size_t)(n0 + row) * 128 + col] = cvt_bf16(acc[mi][nt][r] + bs[col]);
                    }
                }
            }
        }
        __syncthreads();
    }
}

// ---------- merged epilogue MFMA for both node types ----------
// blocks [0,gA): type a ; [gA,2gA): type b. out = alpha*(T@Wa+ba) + (1-alpha)*h
__global__ __launch_bounds__(256) void mfma_out2_kernel(
        const unsigned short* __restrict__ ta, const unsigned short* __restrict__ tb,
        const unsigned short* __restrict__ WaT, const float* __restrict__ ba,
        const float* __restrict__ h_a, const float* __restrict__ h_b,
        const float* __restrict__ skipv, float* __restrict__ outbase,
        int nrows, int gA) {
    __shared__ unsigned short Xs[128 * LPAD];
    __shared__ unsigned short Ws[128 * LPAD];
    __shared__ float bs[128];
    int tid = threadIdx.x;
    int sel = blockIdx.x >= gA;
    int n0 = (sel ? blockIdx.x - gA : blockIdx.x) * 128;
    const unsigned short* T16 = sel ? tb : ta;
    const unsigned short* W = WaT + sel * 16384;
    const float* bias = ba + sel * 128;
    const float* resid = sel ? h_b : h_a;
    float* out = outbase + (size_t)sel * nrows * 128;
    int rows_in = nrows - n0; if (rows_in > 128) rows_in = 128;

    {
        int rowb = tid >> 4, seg = tid & 15;
#pragma unroll
        for (int p = 0; p < 8; ++p) {
            int row = p * 16 + rowb;
            int rowg = row < rows_in ? row : rows_in - 1;
            uint4 d = *(const uint4*)(T16 + ((size_t)(n0 + rowg)) * 128 + seg * 8);
            *(uint4*)&Xs[row * LPAD + seg * 8] = d;
            uint4 w = *(const uint4*)(W + (size_t)row * 128 + seg * 8);
            *(uint4*)&Ws[row * LPAD + seg * 8] = w;
        }
        if (tid < 128) bs[tid] = bias[tid];
    }
    __syncthreads();

    int wave = tid >> 6, lane = tid & 63;
    int l15 = lane & 15, quad = lane >> 4;

    f32x4 acc[2][8];
#pragma unroll
    for (int mi = 0; mi < 2; ++mi)
#pragma unroll
        for (int nt = 0; nt < 8; ++nt) acc[mi][nt] = (f32x4){0.f, 0.f, 0.f, 0.f};

#pragma unroll
    for (int ks = 0; ks < 4; ++ks) {
        bf16x8 afr[2];
        afr[0] = *(const bf16x8*)&Xs[(wave * 32 + l15) * LPAD + ks * 32 + quad * 8];
        afr[1] = *(const bf16x8*)&Xs[(wave * 32 + 16 + l15) * LPAD + ks * 32 + quad * 8];
#pragma unroll
        for (int nt = 0; nt < 8; ++nt) {
            bf16x8 bfr = *(const bf16x8*)&Ws[(nt * 16 + l15) * LPAD + ks * 32 + quad * 8];
            acc[0][nt] = __builtin_amdgcn_mfma_f32_16x16x32_bf16(afr[0], bfr, acc[0][nt], 0, 0, 0);
            acc[1][nt] = __builtin_amdgcn_mfma_f32_16x16x32_bf16(afr[1], bfr, acc[1][nt], 0, 0, 0);
        }
    }

    float s = skipv[sel];
    float alpha = 1.f / (1.f + __expf(-s));
    float beta = 1.f - alpha;
#pragma unroll
    for (int mi = 0; mi < 2; ++mi) {
        int rowbase = wave * 32 + mi * 16 + quad * 4;
#pragma unroll
        for (int r = 0; r < 4; ++r) {
            int row = rowbase + r;
            if (row < rows_in) {
#pragma unroll
                for (int nt = 0; nt < 8; ++nt) {
                    int col = nt * 16 + l15;
                    size_t gi = (size_t)(n0 + row) * 128 + col;
                    out[gi] = alpha * (acc[mi][nt][r] + bs[col]) + beta * resid[gi];
                }
            }
        }
    }
}

// ---------- fused CSR build for all 3 relations ----------
// cnt3/offs3/fill3 are [3][N]; ss3 is [3][E]. Per-relation offsets are 0-based.
__global__ void count3_kernel(const int* __restrict__ d0, const int* __restrict__ d1,
                              const int* __restrict__ d2, int* __restrict__ cnt3,
                              int E, int N) {
    int t = blockIdx.x * 256 + threadIdx.x;
    if (t >= 3 * E) return;
    int r = (t >= 2 * E) ? 2 : (t >= E ? 1 : 0);
    int e = t - r * E;
    const int* d = (r == 0) ? d0 : ((r == 1) ? d1 : d2);
    atomicAdd(&cnt3[r * N + d[e]], 1);
}

#define SCAN_B 256
__global__ void scan1_kernel(const int* __restrict__ cnt, int* __restrict__ offs,
                             int* __restrict__ bsum, int n) {
    __shared__ int sh[SCAN_B];
    int rbase = blockIdx.y * n;
    int i = blockIdx.x * SCAN_B + threadIdx.x;
    int v = (i < n) ? cnt[rbase + i] : 0;
    sh[threadIdx.x] = v;
    __syncthreads();
    for (int off = 1; off < SCAN_B; off <<= 1) {
        int t = (threadIdx.x >= off) ? sh[threadIdx.x - off] : 0;
        __syncthreads();
        sh[threadIdx.x] += t;
        __syncthreads();
    }
    if (i < n) offs[rbase + i] = sh[threadIdx.x] - v;
    if (threadIdx.x == SCAN_B - 1) bsum[blockIdx.y * 512 + blockIdx.x] = sh[threadIdx.x];
}

__global__ void scan2_kernel(int* __restrict__ bsum, int nb) {
    __shared__ int sh[512];
    int* bs = bsum + blockIdx.x * 512;
    int v = (threadIdx.x < nb) ? bs[threadIdx.x] : 0;
    sh[threadIdx.x] = v;
    __syncthreads();
    for (int off = 1; off < 512; off <<= 1) {
        int t = (threadIdx.x >= off) ? sh[threadIdx.x - off] : 0;
        __syncthreads();
        sh[threadIdx.x] += t;
        __syncthreads();
    }
    if (threadIdx.x < nb) bs[threadIdx.x] = sh[threadIdx.x] - v;
}

__global__ void scan3_kernel(int* __restrict__ offs, const int* __restrict__ bsum,
                             int* __restrict__ fill, int n) {
    int rbase = blockIdx.y * n;
    int i = blockIdx.x * SCAN_B + threadIdx.x;
    if (i < n) {
        int o = offs[rbase + i] + bsum[blockIdx.y * 512 + blockIdx.x];
        offs[rbase + i] = o;
        fill[rbase + i] = o;
    }
}

__global__ void scatter3_kernel(const int* __restrict__ s0, const int* __restrict__ d0,
                                const int* __restrict__ s1, const int* __restrict__ d1,
                                const int* __restrict__ s2, const int* __restrict__ d2,
                                int* __restrict__ fill3, int* __restrict__ ss3,
                                int E, int N) {
    int t = blockIdx.x * 256 + threadIdx.x;
    if (t >= 3 * E) return;
    int r = (t >= 2 * E) ? 2 : (t >= E ? 1 : 0);
    int e = t - r * E;
    const int* sp = (r == 0) ? s0 : ((r == 1) ? s1 : s2);
    const int* dp = (r == 0) ? d0 : ((r == 1) ? d1 : d2);
    int p = atomicAdd(&fill3[r * N + dp[e]], 1);
    ss3[(size_t)r * E + p] = sp[e];
}

// ---------- fused aggregation, 32 lanes per node, dual-issue gathers ----------
// 32-lane group per node: lane = j*8 + h (j = edge slot 0..3, h = head 0..7).
// No-max softmax (scores ~N(0,1); exp() can't overflow f32).
// Even blocks: b-nodes — r0 and r2 INTERLEAVED in one predicated loop so both
//   relations' ss + k/v loads are in flight together (2x memory parallelism);
//   inactive slots clamp to row 0 and select exp->0.
// Odd blocks: a-nodes — r1 with 2 edges per lane in flight per iteration.
// Block sides interleaved by parity so long b-blocks and short a-blocks mix
// on CUs throughout the dispatch (no b-only tail).
__device__ __forceinline__ void load_q(const unsigned short* __restrict__ q,
                                       int wid, int h, f32x2* q2) {
    const uint4* qp = (const uint4*)(q + (size_t)wid * 128 + h * 16);
    uint4 qa = qp[0], qb = qp[1];
    q2[0] = bf16pair(qa.x); q2[1] = bf16pair(qa.y);
    q2[2] = bf16pair(qa.z); q2[3] = bf16pair(qa.w);
    q2[4] = bf16pair(qb.x); q2[5] = bf16pair(qb.y);
    q2[6] = bf16pair(qb.z); q2[7] = bf16pair(qb.w);
}

__device__ __forceinline__ void store_bf16(unsigned short* __restrict__ outp,
                                           size_t base, const float* o) {
    unsigned short* op = outp + base;
    ushort4 p0, p1, p2, p3;
    p0.x = cvt_bf16(o[0]);  p0.y = cvt_bf16(o[1]);  p0.z = cvt_bf16(o[2]);  p0.w = cvt_bf16(o[3]);
    p1.x = cvt_bf16(o[4]);  p1.y = cvt_bf16(o[5]);  p1.z = cvt_bf16(o[6]);  p1.w = cvt_bf16(o[7]);
    p2.x = cvt_bf16(o[8]);  p2.y = cvt_bf16(o[9]);  p2.z = cvt_bf16(o[10]); p2.w = cvt_bf16(o[11]);
    p3.x = cvt_bf16(o[12]); p3.y = cvt_bf16(o[13]); p3.z = cvt_bf16(o[14]); p3.w = cvt_bf16(o[15]);
    ((ushort4*)op)[0] = p0; ((ushort4*)op)[1] = p1;
    ((ushort4*)op)[2] = p2; ((ushort4*)op)[3] = p3;
}

#define DOT8(d, q2, A, B) \
    d = (f32x2){0.f, 0.f}; \
    d += q2[0] * bf16pair(A.x); d += q2[1] * bf16pair(A.y); \
    d += q2[2] * bf16pair(A.z); d += q2[3] * bf16pair(A.w); \
    d += q2[4] * bf16pair(B.x); d += q2[5] * bf16pair(B.y); \
    d += q2[6] * bf16pair(B.z); d += q2[7] * bf16pair(B.w);

#define ACC8(acc, ex, A, B) { \
    f32x2 _e = (f32x2){ex, ex}; \
    acc[0] += _e * bf16pair(A.x); acc[1] += _e * bf16pair(A.y); \
    acc[2] += _e * bf16pair(A.z); acc[3] += _e * bf16pair(A.w); \
    acc[4] += _e * bf16pair(B.x); acc[5] += _e * bf16pair(B.y); \
    acc[6] += _e * bf16pair(B.z); acc[7] += _e * bf16pair(B.w); }

__global__ __launch_bounds__(256) void agg_fused_kernel(
    const unsigned short* __restrict__ qb,
    const unsigned short* __restrict__ k0, const unsigned short* __restrict__ v0,
    const int* __restrict__ offs0, const int* __restrict__ cnt0, const int* __restrict__ ss0,
    const unsigned short* __restrict__ k2, const unsigned short* __restrict__ v2,
    const int* __restrict__ offs2, const int* __restrict__ cnt2, const int* __restrict__ ss2,
    const unsigned short* __restrict__ qa,
    const unsigned short* __restrict__ k1, const unsigned short* __restrict__ v1,
    const int* __restrict__ offs1, const int* __restrict__ cnt1, const int* __restrict__ ss1,
    unsigned short* __restrict__ tb16, unsigned short* __restrict__ ta16,
    int N) {
    int side = blockIdx.x & 1;          // 0: b-nodes, 1: a-nodes (interleaved)
    int bidx = blockIdx.x >> 1;
    int l32 = threadIdx.x & 31;
    int j = l32 >> 3, h = l32 & 7;
    int wid = (bidx * 256 + (int)threadIdx.x) >> 5;
    if (wid >= N) return;

    if (side == 0) {
        // ---- b-side: r0 and r2 interleaved, shared q_b ----
        int start0 = offs0[wid], deg0 = cnt0[wid];
        int start2 = offs2[wid], deg2 = cnt2[wid];
        f32x2 q2[8];
        load_q(qb, wid, h, q2);

        float den0 = 0.f, den2 = 0.f;
        f32x2 a0[8], a2[8];
#pragma unroll
        for (int t = 0; t < 8; ++t) { a0[t] = (f32x2){0.f, 0.f}; a2[t] = (f32x2){0.f, 0.f}; }

        int i0 = j, i2 = j;
        while ((i0 < deg0) || (i2 < deg2)) {
            bool c0 = i0 < deg0, c2 = i2 < deg2;
            int s0 = c0 ? ss0[start0 + i0] : 0;
            int s2 = c2 ? ss2[start2 + i2] : 0;
            const uint4* k0p = (const uint4*)(k0 + (size_t)s0 * 128 + h * 16);
            const uint4* v0p = (const uint4*)(v0 + (size_t)s0 * 128 + h * 16);
            const uint4* k2p = (const uint4*)(k2 + (size_t)s2 * 128 + h * 16);
            const uint4* v2p = (const uint4*)(v2 + (size_t)s2 * 128 + h * 16);
            uint4 kA0 = k0p[0], kB0 = k0p[1], vA0 = v0p[0], vB0 = v0p[1];
            uint4 kA2 = k2p[0], kB2 = k2p[1], vA2 = v2p[0], vB2 = v2p[1];

            f32x2 d0, d2v;
            DOT8(d0, q2, kA0, kB0);
            DOT8(d2v, q2, kA2, kB2);
            float ex0 = c0 ? __expf(d0.x + d0.y) : 0.f;
            float ex2 = c2 ? __expf(d2v.x + d2v.y) : 0.f;
            den0 += ex0; den2 += ex2;
            ACC8(a0, ex0, vA0, vB0);
            ACC8(a2, ex2, vA2, vB2);
            i0 += 4; i2 += 4;
        }

        // combine across j (masks 8,16 stay inside the 32-lane group)
#pragma unroll
        for (int mask = 8; mask <= 16; mask <<= 1) {
            den0 += __shfl_xor(den0, mask);
            den2 += __shfl_xor(den2, mask);
#pragma unroll
            for (int t = 0; t < 8; ++t) {
                a0[t].x += __shfl_xor(a0[t].x, mask);
                a0[t].y += __shfl_xor(a0[t].y, mask);
                a2[t].x += __shfl_xor(a2[t].x, mask);
                a2[t].y += __shfl_xor(a2[t].y, mask);
            }
        }

        if (j == 0) {
            float i0s = (deg0 > 0) ? (0.5f / den0) : 0.f;
            float i2s = (deg2 > 0) ? (0.5f / den2) : 0.f;
            float o[16];
#pragma unroll
            for (int t = 0; t < 8; ++t) {
                o[2 * t]     = a0[t].x * i0s + a2[t].x * i2s;
                o[2 * t + 1] = a0[t].y * i0s + a2[t].y * i2s;
            }
            store_bf16(tb16, (size_t)wid * 128 + h * 16, o);
        }
    } else {
        // ---- a-side: relation 1, 2 edges per lane in flight ----
        int start1 = offs1[wid], deg1 = cnt1[wid];
        f32x2 q2[8];
        load_q(qa, wid, h, q2);

        float den = 0.f;
        f32x2 ac[8];
#pragma unroll
        for (int t = 0; t < 8; ++t) ac[t] = (f32x2){0.f, 0.f};

        for (int i = j; i < deg1; i += 8) {
            int iB = i + 4;
            bool cB = iB < deg1;
            int sA = ss1[start1 + i];
            int sB = cB ? ss1[start1 + iB] : 0;
            const uint4* kAp = (const uint4*)(k1 + (size_t)sA * 128 + h * 16);
            const uint4* vAp = (const uint4*)(v1 + (size_t)sA * 128 + h * 16);
            const uint4* kBp = (const uint4*)(k1 + (size_t)sB * 128 + h * 16);
            const uint4* vBp = (const uint4*)(v1 + (size_t)sB * 128 + h * 16);
            uint4 kAa = kAp[0], kAb = kAp[1], vAa = vAp[0], vAb = vAp[1];
            uint4 kBa = kBp[0], kBb = kBp[1], vBa = vBp[0], vBb = vBp[1];

            f32x2 dA, dB;
            DOT8(dA, q2, kAa, kAb);
            DOT8(dB, q2, kBa, kBb);
            float exA = __expf(dA.x + dA.y);
            float exB = cB ? __expf(dB.x + dB.y) : 0.f;
            den += exA + exB;
            ACC8(ac, exA, vAa, vAb);
            ACC8(ac, exB, vBa, vBb);
        }

#pragma unroll
        for (int mask = 8; mask <= 16; mask <<= 1) {
            den += __shfl_xor(den, mask);
#pragma unroll
            for (int t = 0; t < 8; ++t) {
                ac[t].x += __shfl_xor(ac[t].x, mask);
                ac[t].y += __shfl_xor(ac[t].y, mask);
            }
        }

        if (j == 0) {
            float inv = (deg1 > 0) ? (1.0f / den) : 0.f;
            float o[16];
#pragma unroll
            for (int t = 0; t < 8; ++t) {
                o[2 * t]     = ac[t].x * inv;
                o[2 * t + 1] = ac[t].y * inv;
            }
            store_bf16(ta16, (size_t)wid * 128 + h * 16, o);
        }
    }
}

// ---------- launch ----------
extern "C" void kernel_launch(void* const* d_in, const int* in_sizes, int n_in,
                              void* d_out, int out_size, void* d_ws, size_t ws_size,
                              hipStream_t stream) {
    const float* h_a = (const float*)d_in[0];
    const float* h_b = (const float*)d_in[1];
    const int* srcs[3] = {(const int*)d_in[2], (const int*)d_in[4], (const int*)d_in[6]};
    const int* dsts[3] = {(const int*)d_in[3], (const int*)d_in[5], (const int*)d_in[7]};
    const float* Wk = (const float*)d_in[8];
    const float* bk = (const float*)d_in[9];
    const float* Wv = (const float*)d_in[10];
    const float* bv = (const float*)d_in[11];
    const float* Wq = (const float*)d_in[12];
    const float* bq = (const float*)d_in[13];
    const float* Wa = (const float*)d_in[14];
    const float* ba = (const float*)d_in[15];
    const float* att = (const float*)d_in[16];
    const float* msg = (const float*)d_in[17];
    const float* pri = (const float*)d_in[18];
    const float* skip = (const float*)d_in[19];

    const int N = in_sizes[0] / 128;
    const int E = in_sizes[2];
    const size_t NC = (size_t)N * 128;

    char* P = (char*)d_ws;
    auto alloc = [&](size_t bytes) { char* p = P; P += (bytes + 255) & ~(size_t)255; return p; };

    unsigned short* WkT = (unsigned short*)alloc(3 * 16384 * 2);
    unsigned short* WvT = (unsigned short*)alloc(3 * 16384 * 2);
    unsigned short* WqT = (unsigned short*)alloc(2 * 16384 * 2);
    unsigned short* WaT = (unsigned short*)alloc(2 * 16384 * 2);
    float* bkC = (float*)alloc(3 * 128 * 4);
    float* bvC = (float*)alloc(3 * 128 * 4);
    unsigned short* qa16 = (unsigned short*)alloc(NC * 2);
    unsigned short* qb16 = (unsigned short*)alloc(NC * 2);
    unsigned short* k16[3], *v16[3];
    for (int r = 0; r < 3; ++r) {
        k16[r] = (unsigned short*)alloc(NC * 2);
        v16[r] = (unsigned short*)alloc(NC * 2);
    }
    unsigned short* ta16 = (unsigned short*)alloc(NC * 2);
    unsigned short* tb16 = (unsigned short*)alloc(NC * 2);
    int* cnt3 = (int*)alloc((size_t)3 * N * 4);
    int* offs3 = (int*)alloc((size_t)3 * N * 4);
    int* fill3 = (int*)alloc((size_t)3 * N * 4);
    int* ss3 = (int*)alloc((size_t)3 * E * 4);
    int* bsum = (int*)alloc(3 * 512 * 4);

    int eb3 = (3 * E + 255) / 256;
    int scanb = (N + SCAN_B - 1) / SCAN_B;

    // fused CSR for all 3 relations
    hipMemsetAsync(cnt3, 0, (size_t)3 * N * sizeof(int), stream);
    count3_kernel<<<eb3, 256, 0, stream>>>(dsts[0], dsts[1], dsts[2], cnt3, E, N);
    scan1_kernel<<<dim3(scanb, 3), SCAN_B, 0, stream>>>(cnt3, offs3, bsum, N);
    scan2_kernel<<<3, 512, 0, stream>>>(bsum, scanb);
    scan3_kernel<<<dim3(scanb, 3), SCAN_B, 0, stream>>>(offs3, bsum, fill3, N);
    scatter3_kernel<<<eb3, 256, 0, stream>>>(srcs[0], dsts[0], srcs[1], dsts[1],
                                             srcs[2], dsts[2], fill3, ss3, E, N);

    // weight prep
    compose_kernel<<<(3 * 16384 + 255) / 256, 256, 0, stream>>>(
        Wk, bk, Wv, bv, att, msg, pri, WkT, WvT, bkC, bvC);
    tcast4_kernel<<<dim3(64, 4), 256, 0, stream>>>(Wq, Wa, WqT, WaT);

    int gblocks = (N + 127) / 128;

    // merged projections (f32 inputs, cast fused into staging)
    OutSpecs8 s8;
    s8.o[0] = {WqT, bq, qa16};
    s8.o[1] = {WkT + 0 * 16384, bkC + 0 * 128, k16[0]};
    s8.o[2] = {WvT + 0 * 16384, bvC + 0 * 128, v16[0]};
    s8.o[3] = {WkT + 2 * 16384, bkC + 2 * 128, k16[2]};
    s8.o[4] = {WvT + 2 * 16384, bvC + 2 * 128, v16[2]};
    s8.o[5] = {WqT + 16384, bq + 128, qb16};
    s8.o[6] = {WkT + 1 * 16384, bkC + 1 * 128, k16[1]};
    s8.o[7] = {WvT + 1 * 16384, bvC + 1 * 128, v16[1]};
    mfma_proj2_kernel<<<2 * gblocks, 256, 0, stream>>>(h_a, h_b, N, s8, gblocks);

    // fused aggregation: 32-lane group per node, sides interleaved by parity
    int bblk = (N + 7) / 8;   // 8 nodes per 256-thread block per side
    agg_fused_kernel<<<2 * bblk, 256, 0, stream>>>(
        qb16, k16[0], v16[0], offs3 + 0 * N, cnt3 + 0 * N, ss3 + 0 * (size_t)E,
        k16[2], v16[2], offs3 + 2 * N, cnt3 + 2 * N, ss3 + 2 * (size_t)E,
        qa16, k16[1], v16[1], offs3 + 1 * N, cnt3 + 1 * N, ss3 + 1 * (size_t)E,
        tb16, ta16, N);

    // merged epilogue
    mfma_out2_kernel<<<2 * gblocks, 256, 0, stream>>>(
        ta16, tb16, WaT, ba, h_a, h_b, skip, (float*)d_out, N, gblocks);
}

// Round 9
// 640.663 us; speedup vs baseline: 1.0688x; 1.0688x over previous
//
#include <hip/hip_runtime.h>
#include <math.h>

typedef short bf16x8 __attribute__((ext_vector_type(8)));
typedef float f32x4 __attribute__((ext_vector_type(4)));
typedef float f32x2 __attribute__((ext_vector_type(2)));

__device__ __forceinline__ unsigned short cvt_bf16(float f) {
    unsigned u = __float_as_uint(f);
    u += 0x7fffu + ((u >> 16) & 1);        // round-to-nearest-even
    return (unsigned short)(u >> 16);
}
__device__ __forceinline__ float cvt_f32(unsigned short b) {
    return __uint_as_float(((unsigned)b) << 16);
}
// bf16 pair (packed in one u32) -> 2 floats in 2 VALU ops
__device__ __forceinline__ f32x2 bf16pair(unsigned u) {
    f32x2 r;
    r.x = __uint_as_float(u << 16);
    r.y = __uint_as_float(u & 0xffff0000u);
    return r;
}

// ---------- compose relation weights, store TRANSPOSED bf16 [c][i] ----------
// k' = x @ (Wk . blockdiag(att)) * pri/4 ; v' = x @ (Wv . blockdiag(msg))
__global__ void compose_kernel(const float* __restrict__ Wk, const float* __restrict__ bk,
                               const float* __restrict__ Wv, const float* __restrict__ bv,
                               const float* __restrict__ att, const float* __restrict__ msg,
                               const float* __restrict__ pri,
                               unsigned short* __restrict__ WkT, unsigned short* __restrict__ WvT,
                               float* __restrict__ bkC, float* __restrict__ bvC) {
    int tid = blockIdx.x * blockDim.x + threadIdx.x;
    if (tid >= 3 * 16384) return;
    int r = tid / 16384;
    int rem = tid & 16383;
    int c = rem >> 7;       // output dim (row of W^T)
    int i = rem & 127;      // input dim
    int h = c >> 4, e = c & 15;
    int wsel = (r == 1) ? 1 : 0;
    float p = pri[r * 8 + h] * 0.25f;   // 1/sqrt(16)

    const float* wkrow = Wk + wsel * 16384 + i * 128 + h * 16;
    const float* wvrow = Wv + wsel * 16384 + i * 128 + h * 16;
    const float* attc = att + ((r * 8 + h) * 16) * 16 + e;
    const float* msgc = msg + ((r * 8 + h) * 16) * 16 + e;
    float aK = 0.f, aV = 0.f;
#pragma unroll
    for (int d = 0; d < 16; ++d) {
        aK += wkrow[d] * attc[d * 16];
        aV += wvrow[d] * msgc[d * 16];
    }
    WkT[r * 16384 + c * 128 + i] = cvt_bf16(aK * p);
    WvT[r * 16384 + c * 128 + i] = cvt_bf16(aV);
    if (i == 0) {
        const float* bkr = bk + wsel * 128 + h * 16;
        const float* bvr = bv + wsel * 128 + h * 16;
        float bK = 0.f, bV = 0.f;
#pragma unroll
        for (int d = 0; d < 16; ++d) {
            bK += bkr[d] * attc[d * 16];
            bV += bvr[d] * msgc[d * 16];
        }
        bkC[r * 128 + c] = bK * p;
        bvC[r * 128 + c] = bV;
    }
}

// ---------- transpose+cast 4 128x128 f32 matrices (Wq[0],Wq[1],Wa[0],Wa[1]) ----------
__global__ void tcast4_kernel(const float* __restrict__ Wq, const float* __restrict__ Wa,
                              unsigned short* __restrict__ WqT, unsigned short* __restrict__ WaT) {
    int m = blockIdx.y;
    const float* src = (m < 2) ? Wq + m * 16384 : Wa + (m - 2) * 16384;
    unsigned short* dst = (m < 2) ? WqT + m * 16384 : WaT + (m - 2) * 16384;
    int tid = blockIdx.x * 256 + threadIdx.x;   // 16384 per matrix
    int c = tid >> 7, i = tid & 127;
    dst[tid] = cvt_bf16(src[i * 128 + c]);      // dst[c][i] = src[i][c]
}

// ---------- merged multi-output MFMA projection over BOTH node types ----------
// X is f32 (cast fused into LDS staging). Blocks [0,gA): X=h_a, outputs 0..4 ;
// blocks [gA,2gA): X=h_b, outputs 5..7.
struct OutSpec { const unsigned short* Wt; const float* bias; unsigned short* out; };
struct OutSpecs8 { OutSpec o[8]; };

#define LPAD 136   // 128 + 8 bf16 pad: row stride 272 B -> bank step 4, 2-way (free)

__global__ __launch_bounds__(256) void mfma_proj2_kernel(const float* __restrict__ Xa,
                                                         const float* __restrict__ Xb,
                                                         int nrows, OutSpecs8 specs, int gA) {
    __shared__ unsigned short Xs[128 * LPAD];
    __shared__ unsigned short Ws[128 * LPAD];
    __shared__ float bs[128];
    int tid = threadIdx.x;
    int aSide = blockIdx.x < gA;
    const float* X = aSide ? Xa : Xb;
    int obase = aSide ? 0 : 5;
    int nout = aSide ? 5 : 3;
    int n0 = (aSide ? blockIdx.x : blockIdx.x - gA) * 128;
    int rows_in = nrows - n0; if (rows_in > 128) rows_in = 128;

    {   // stage X tile from f32, converting to bf16 (row-clamped for partial block)
        int rowb = tid >> 4, seg = tid & 15;
#pragma unroll
        for (int p = 0; p < 8; ++p) {
            int row = p * 16 + rowb;
            int rowg = row < rows_in ? row : rows_in - 1;
            const float* src = X + ((size_t)(n0 + rowg)) * 128 + seg * 8;
            float4 f0 = ((const float4*)src)[0];
            float4 f1 = ((const float4*)src)[1];
            ushort4 o0, o1;
            o0.x = cvt_bf16(f0.x); o0.y = cvt_bf16(f0.y); o0.z = cvt_bf16(f0.z); o0.w = cvt_bf16(f0.w);
            o1.x = cvt_bf16(f1.x); o1.y = cvt_bf16(f1.y); o1.z = cvt_bf16(f1.z); o1.w = cvt_bf16(f1.w);
            *(ushort4*)&Xs[row * LPAD + seg * 8] = o0;
            *(ushort4*)&Xs[row * LPAD + seg * 8 + 4] = o1;
        }
    }

    int wave = tid >> 6, lane = tid & 63;
    int l15 = lane & 15, quad = lane >> 4;

    for (int oo = 0; oo < nout; ++oo) {
        const unsigned short* Wt = specs.o[obase + oo].Wt;
        const float* bias = specs.o[obase + oo].bias;
        unsigned short* out = specs.o[obase + oo].out;
        {   // stage W^T
            int rowb = tid >> 4, seg = tid & 15;
#pragma unroll
            for (int p = 0; p < 8; ++p) {
                int row = p * 16 + rowb;
                uint4 d = *(const uint4*)(Wt + (size_t)row * 128 + seg * 8);
                *(uint4*)&Ws[row * LPAD + seg * 8] = d;
            }
            if (tid < 128) bs[tid] = bias[tid];
        }
        __syncthreads();

        f32x4 acc[2][8];
#pragma unroll
        for (int mi = 0; mi < 2; ++mi)
#pragma unroll
            for (int nt = 0; nt < 8; ++nt) acc[mi][nt] = (f32x4){0.f, 0.f, 0.f, 0.f};

#pragma unroll
        for (int ks = 0; ks < 4; ++ks) {
            bf16x8 afr[2];
            afr[0] = *(const bf16x8*)&Xs[(wave * 32 + l15) * LPAD + ks * 32 + quad * 8];
            afr[1] = *(const bf16x8*)&Xs[(wave * 32 + 16 + l15) * LPAD + ks * 32 + quad * 8];
#pragma unroll
            for (int nt = 0; nt < 8; ++nt) {
                bf16x8 bfr = *(const bf16x8*)&Ws[(nt * 16 + l15) * LPAD + ks * 32 + quad * 8];
                acc[0][nt] = __builtin_amdgcn_mfma_f32_16x16x32_bf16(afr[0], bfr, acc[0][nt], 0, 0, 0);
                acc[1][nt] = __builtin_amdgcn_mfma_f32_16x16x32_bf16(afr[1], bfr, acc[1][nt], 0, 0, 0);
            }
        }

#pragma unroll
        for (int mi = 0; mi < 2; ++mi) {
            int rowbase = wave * 32 + mi * 16 + quad * 4;
#pragma unroll
            for (int r = 0; r < 4; ++r) {
                int row = rowbase + r;
                if (row < rows_in) {
#pragma unroll
                    for (int nt = 0; nt < 8; ++nt) {
                        int col = nt * 16 + l15;
                        out[(size_t)(n0 + row) * 128 + col] = cvt_bf16(acc[mi][nt][r] + bs[col]);
                    }
                }
            }
        }
        __syncthreads();
    }
}

// ---------- merged epilogue MFMA for both node types ----------
// blocks [0,gA): type a ; [gA,2gA): type b. out = alpha*(T@Wa+ba) + (1-alpha)*h
__global__ __launch_bounds__(256) void mfma_out2_kernel(
        const unsigned short* __restrict__ ta, const unsigned short* __restrict__ tb,
        const unsigned short* __restrict__ WaT, const float* __restrict__ ba,
        const float* __restrict__ h_a, const float* __restrict__ h_b,
        const float* __restrict__ skipv, float* __restrict__ outbase,
        int nrows, int gA) {
    __shared__ unsigned short Xs[128 * LPAD];
    __shared__ unsigned short Ws[128 * LPAD];
    __shared__ float bs[128];
    int tid = threadIdx.x;
    int sel = blockIdx.x >= gA;
    int n0 = (sel ? blockIdx.x - gA : blockIdx.x) * 128;
    const unsigned short* T16 = sel ? tb : ta;
    const unsigned short* W = WaT + sel * 16384;
    const float* bias = ba + sel * 128;
    const float* resid = sel ? h_b : h_a;
    float* out = outbase + (size_t)sel * nrows * 128;
    int rows_in = nrows - n0; if (rows_in > 128) rows_in = 128;

    {
        int rowb = tid >> 4, seg = tid & 15;
#pragma unroll
        for (int p = 0; p < 8; ++p) {
            int row = p * 16 + rowb;
            int rowg = row < rows_in ? row : rows_in - 1;
            uint4 d = *(const uint4*)(T16 + ((size_t)(n0 + rowg)) * 128 + seg * 8);
            *(uint4*)&Xs[row * LPAD + seg * 8] = d;
            uint4 w = *(const uint4*)(W + (size_t)row * 128 + seg * 8);
            *(uint4*)&Ws[row * LPAD + seg * 8] = w;
        }
        if (tid < 128) bs[tid] = bias[tid];
    }
    __syncthreads();

    int wave = tid >> 6, lane = tid & 63;
    int l15 = lane & 15, quad = lane >> 4;

    f32x4 acc[2][8];
#pragma unroll
    for (int mi = 0; mi < 2; ++mi)
#pragma unroll
        for (int nt = 0; nt < 8; ++nt) acc[mi][nt] = (f32x4){0.f, 0.f, 0.f, 0.f};

#pragma unroll
    for (int ks = 0; ks < 4; ++ks) {
        bf16x8 afr[2];
        afr[0] = *(const bf16x8*)&Xs[(wave * 32 + l15) * LPAD + ks * 32 + quad * 8];
        afr[1] = *(const bf16x8*)&Xs[(wave * 32 + 16 + l15) * LPAD + ks * 32 + quad * 8];
#pragma unroll
        for (int nt = 0; nt < 8; ++nt) {
            bf16x8 bfr = *(const bf16x8*)&Ws[(nt * 16 + l15) * LPAD + ks * 32 + quad * 8];
            acc[0][nt] = __builtin_amdgcn_mfma_f32_16x16x32_bf16(afr[0], bfr, acc[0][nt], 0, 0, 0);
            acc[1][nt] = __builtin_amdgcn_mfma_f32_16x16x32_bf16(afr[1], bfr, acc[1][nt], 0, 0, 0);
        }
    }

    float s = skipv[sel];
    float alpha = 1.f / (1.f + __expf(-s));
    float beta = 1.f - alpha;
#pragma unroll
    for (int mi = 0; mi < 2; ++mi) {
        int rowbase = wave * 32 + mi * 16 + quad * 4;
#pragma unroll
        for (int r = 0; r < 4; ++r) {
            int row = rowbase + r;
            if (row < rows_in) {
#pragma unroll
                for (int nt = 0; nt < 8; ++nt) {
                    int col = nt * 16 + l15;
                    size_t gi = (size_t)(n0 + row) * 128 + col;
                    out[gi] = alpha * (acc[mi][nt][r] + bs[col]) + beta * resid[gi];
                }
            }
        }
    }
}

// ---------- fused CSR build for all 3 relations ----------
// cnt3/offs3/fill3 are [3][N]; ss3 is [3][E]. Per-relation offsets are 0-based.
__global__ void count3_kernel(const int* __restrict__ d0, const int* __restrict__ d1,
                              const int* __restrict__ d2, int* __restrict__ cnt3,
                              int E, int N) {
    int t = blockIdx.x * 256 + threadIdx.x;
    if (t >= 3 * E) return;
    int r = (t >= 2 * E) ? 2 : (t >= E ? 1 : 0);
    int e = t - r * E;
    const int* d = (r == 0) ? d0 : ((r == 1) ? d1 : d2);
    atomicAdd(&cnt3[r * N + d[e]], 1);
}

#define SCAN_B 256
__global__ void scan1_kernel(const int* __restrict__ cnt, int* __restrict__ offs,
                             int* __restrict__ bsum, int n) {
    __shared__ int sh[SCAN_B];
    int rbase = blockIdx.y * n;
    int i = blockIdx.x * SCAN_B + threadIdx.x;
    int v = (i < n) ? cnt[rbase + i] : 0;
    sh[threadIdx.x] = v;
    __syncthreads();
    for (int off = 1; off < SCAN_B; off <<= 1) {
        int t = (threadIdx.x >= off) ? sh[threadIdx.x - off] : 0;
        __syncthreads();
        sh[threadIdx.x] += t;
        __syncthreads();
    }
    if (i < n) offs[rbase + i] = sh[threadIdx.x] - v;
    if (threadIdx.x == SCAN_B - 1) bsum[blockIdx.y * 512 + blockIdx.x] = sh[threadIdx.x];
}

__global__ void scan2_kernel(int* __restrict__ bsum, int nb) {
    __shared__ int sh[512];
    int* bs = bsum + blockIdx.x * 512;
    int v = (threadIdx.x < nb) ? bs[threadIdx.x] : 0;
    sh[threadIdx.x] = v;
    __syncthreads();
    for (int off = 1; off < 512; off <<= 1) {
        int t = (threadIdx.x >= off) ? sh[threadIdx.x - off] : 0;
        __syncthreads();
        sh[threadIdx.x] += t;
        __syncthreads();
    }
    if (threadIdx.x < nb) bs[threadIdx.x] = sh[threadIdx.x] - v;
}

__global__ void scan3_kernel(int* __restrict__ offs, const int* __restrict__ bsum,
                             int* __restrict__ fill, int n) {
    int rbase = blockIdx.y * n;
    int i = blockIdx.x * SCAN_B + threadIdx.x;
    if (i < n) {
        int o = offs[rbase + i] + bsum[blockIdx.y * 512 + blockIdx.x];
        offs[rbase + i] = o;
        fill[rbase + i] = o;
    }
}

__global__ void scatter3_kernel(const int* __restrict__ s0, const int* __restrict__ d0,
                                const int* __restrict__ s1, const int* __restrict__ d1,
                                const int* __restrict__ s2, const int* __restrict__ d2,
                                int* __restrict__ fill3, int* __restrict__ ss3,
                                int E, int N) {
    int t = blockIdx.x * 256 + threadIdx.x;
    if (t >= 3 * E) return;
    int r = (t >= 2 * E) ? 2 : (t >= E ? 1 : 0);
    int e = t - r * E;
    const int* sp = (r == 0) ? s0 : ((r == 1) ? s1 : s2);
    const int* dp = (r == 0) ? d0 : ((r == 1) ? d1 : d2);
    int p = atomicAdd(&fill3[r * N + dp[e]], 1);
    ss3[(size_t)r * E + p] = sp[e];
}

// ---------- fused aggregation, 32 lanes per node (round-7 structure) ----------
// 32-lane group per node: lane = j*8 + h (j = edge slot 0..3, h = head 0..7).
// No-max softmax (scores ~N(0,1); exp() can't overflow f32).
// Blocks [0,bblk): b-nodes, r0 then r2 sequentially, shared q_b load,
//   write tb16 = bf16(0.5*t0/den0 + 0.5*t2/den2) directly.
// Blocks [bblk,2*bblk): a-nodes, r1 -> ta16.
// agg_loop prefetches the NEXT trip's ss index so the steady-state critical
// chain is only the k/v gather, not ss-load -> k/v-load serially.
struct AggSt { float den; f32x2 acc[8]; };

__device__ __forceinline__ void agg_loop(const unsigned short* __restrict__ k,
                                         const unsigned short* __restrict__ v,
                                         const int* __restrict__ ss,
                                         int start, int deg, int j, int h,
                                         const f32x2* q2, AggSt& st) {
    st.den = 0.f;
#pragma unroll
    for (int t = 0; t < 8; ++t) st.acc[t] = (f32x2){0.f, 0.f};
    int s = (j < deg) ? ss[start + j] : 0;
    for (int i = j; i < deg; i += 4) {
        int inext = i + 4;
        int snext = (inext < deg) ? ss[start + inext] : 0;   // prefetch next index
        const uint4* kp = (const uint4*)(k + (size_t)s * 128 + h * 16);
        uint4 ka = kp[0], kb = kp[1];
        const uint4* vp = (const uint4*)(v + (size_t)s * 128 + h * 16);
        uint4 va = vp[0], vb = vp[1];

        f32x2 d2 = (f32x2){0.f, 0.f};
        d2 += q2[0] * bf16pair(ka.x);
        d2 += q2[1] * bf16pair(ka.y);
        d2 += q2[2] * bf16pair(ka.z);
        d2 += q2[3] * bf16pair(ka.w);
        d2 += q2[4] * bf16pair(kb.x);
        d2 += q2[5] * bf16pair(kb.y);
        d2 += q2[6] * bf16pair(kb.z);
        d2 += q2[7] * bf16pair(kb.w);
        float sc = d2.x + d2.y;
        float ex = __expf(sc);
        st.den += ex;
        f32x2 exv = (f32x2){ex, ex};
        st.acc[0] += exv * bf16pair(va.x);
        st.acc[1] += exv * bf16pair(va.y);
        st.acc[2] += exv * bf16pair(va.z);
        st.acc[3] += exv * bf16pair(va.w);
        st.acc[4] += exv * bf16pair(vb.x);
        st.acc[5] += exv * bf16pair(vb.y);
        st.acc[6] += exv * bf16pair(vb.z);
        st.acc[7] += exv * bf16pair(vb.w);
        s = snext;
    }
}

__device__ __forceinline__ void butterfly32(AggSt& st) {
    // masks 8,16 stay inside each 32-lane group; h bits preserved
#pragma unroll
    for (int mask = 8; mask <= 16; mask <<= 1) {
        st.den += __shfl_xor(st.den, mask);
#pragma unroll
        for (int t = 0; t < 8; ++t) {
            st.acc[t].x += __shfl_xor(st.acc[t].x, mask);
            st.acc[t].y += __shfl_xor(st.acc[t].y, mask);
        }
    }
}

__device__ __forceinline__ void load_q(const unsigned short* __restrict__ q,
                                       int wid, int h, f32x2* q2) {
    const uint4* qp = (const uint4*)(q + (size_t)wid * 128 + h * 16);
    uint4 qa = qp[0], qb = qp[1];
    q2[0] = bf16pair(qa.x); q2[1] = bf16pair(qa.y);
    q2[2] = bf16pair(qa.z); q2[3] = bf16pair(qa.w);
    q2[4] = bf16pair(qb.x); q2[5] = bf16pair(qb.y);
    q2[6] = bf16pair(qb.z); q2[7] = bf16pair(qb.w);
}

__device__ __forceinline__ void store_bf16(unsigned short* __restrict__ outp,
                                           size_t base, const float* o) {
    unsigned short* op = outp + base;
    ushort4 p0, p1, p2, p3;
    p0.x = cvt_bf16(o[0]);  p0.y = cvt_bf16(o[1]);  p0.z = cvt_bf16(o[2]);  p0.w = cvt_bf16(o[3]);
    p1.x = cvt_bf16(o[4]);  p1.y = cvt_bf16(o[5]);  p1.z = cvt_bf16(o[6]);  p1.w = cvt_bf16(o[7]);
    p2.x = cvt_bf16(o[8]);  p2.y = cvt_bf16(o[9]);  p2.z = cvt_bf16(o[10]); p2.w = cvt_bf16(o[11]);
    p3.x = cvt_bf16(o[12]); p3.y = cvt_bf16(o[13]); p3.z = cvt_bf16(o[14]); p3.w = cvt_bf16(o[15]);
    ((ushort4*)op)[0] = p0; ((ushort4*)op)[1] = p1;
    ((ushort4*)op)[2] = p2; ((ushort4*)op)[3] = p3;
}

__global__ __launch_bounds__(256) void agg_fused_kernel(
    const unsigned short* __restrict__ qb,
    const unsigned short* __restrict__ k0, const unsigned short* __restrict__ v0,
    const int* __restrict__ offs0, const int* __restrict__ cnt0, const int* __restrict__ ss0,
    const unsigned short* __restrict__ k2, const unsigned short* __restrict__ v2,
    const int* __restrict__ offs2, const int* __restrict__ cnt2, const int* __restrict__ ss2,
    const unsigned short* __restrict__ qa,
    const unsigned short* __restrict__ k1, const unsigned short* __restrict__ v1,
    const int* __restrict__ offs1, const int* __restrict__ cnt1, const int* __restrict__ ss1,
    unsigned short* __restrict__ tb16, unsigned short* __restrict__ ta16,
    int N, int bblk) {
    int bid = blockIdx.x;
    int l32 = threadIdx.x & 31;
    int j = l32 >> 3, h = l32 & 7;

    if (bid < bblk) {
        // ---- b-side: relations 0 and 2, shared q_b ----
        int wid = (bid * 256 + (int)threadIdx.x) >> 5;
        if (wid >= N) return;
        int start0 = offs0[wid], deg0 = cnt0[wid];
        int start2 = offs2[wid], deg2 = cnt2[wid];
        f32x2 q2[8];
        load_q(qb, wid, h, q2);

        AggSt s0, s2;
        agg_loop(k0, v0, ss0, start0, deg0, j, h, q2, s0);
        agg_loop(k2, v2, ss2, start2, deg2, j, h, q2, s2);
        butterfly32(s0);
        butterfly32(s2);

        if (j == 0) {
            float i0 = (deg0 > 0) ? (0.5f / s0.den) : 0.f;
            float i2 = (deg2 > 0) ? (0.5f / s2.den) : 0.f;
            float o[16];
#pragma unroll
            for (int t = 0; t < 8; ++t) {
                o[2 * t]     = s0.acc[t].x * i0 + s2.acc[t].x * i2;
                o[2 * t + 1] = s0.acc[t].y * i0 + s2.acc[t].y * i2;
            }
            store_bf16(tb16, (size_t)wid * 128 + h * 16, o);
        }
    } else {
        // ---- a-side: relation 1 ----
        int wid = ((bid - bblk) * 256 + (int)threadIdx.x) >> 5;
        if (wid >= N) return;
        int start1 = offs1[wid], deg1 = cnt1[wid];
        f32x2 q2[8];
        load_q(qa, wid, h, q2);

        AggSt s1;
        agg_loop(k1, v1, ss1, start1, deg1, j, h, q2, s1);
        butterfly32(s1);

        if (j == 0) {
            float i1 = (deg1 > 0) ? (1.0f / s1.den) : 0.f;
            float o[16];
#pragma unroll
            for (int t = 0; t < 8; ++t) {
                o[2 * t]     = s1.acc[t].x * i1;
                o[2 * t + 1] = s1.acc[t].y * i1;
            }
            store_bf16(ta16, (size_t)wid * 128 + h * 16, o);
        }
    }
}

// ---------- launch ----------
extern "C" void kernel_launch(void* const* d_in, const int* in_sizes, int n_in,
                              void* d_out, int out_size, void* d_ws, size_t ws_size,
                              hipStream_t stream) {
    const float* h_a = (const float*)d_in[0];
    const float* h_b = (const float*)d_in[1];
    const int* srcs[3] = {(const int*)d_in[2], (const int*)d_in[4], (const int*)d_in[6]};
    const int* dsts[3] = {(const int*)d_in[3], (const int*)d_in[5], (const int*)d_in[7]};
    const float* Wk = (const float*)d_in[8];
    const float* bk = (const float*)d_in[9];
    const float* Wv = (const float*)d_in[10];
    const float* bv = (const float*)d_in[11];
    const float* Wq = (const float*)d_in[12];
    const float* bq = (const float*)d_in[13];
    const float* Wa = (const float*)d_in[14];
    const float* ba = (const float*)d_in[15];
    const float* att = (const float*)d_in[16];
    const float* msg = (const float*)d_in[17];
    const float* pri = (const float*)d_in[18];
    const float* skip = (const float*)d_in[19];

    const int N = in_sizes[0] / 128;
    const int E = in_sizes[2];
    const size_t NC = (size_t)N * 128;

    char* P = (char*)d_ws;
    auto alloc = [&](size_t bytes) { char* p = P; P += (bytes + 255) & ~(size_t)255; return p; };

    unsigned short* WkT = (unsigned short*)alloc(3 * 16384 * 2);
    unsigned short* WvT = (unsigned short*)alloc(3 * 16384 * 2);
    unsigned short* WqT = (unsigned short*)alloc(2 * 16384 * 2);
    unsigned short* WaT = (unsigned short*)alloc(2 * 16384 * 2);
    float* bkC = (float*)alloc(3 * 128 * 4);
    float* bvC = (float*)alloc(3 * 128 * 4);
    unsigned short* qa16 = (unsigned short*)alloc(NC * 2);
    unsigned short* qb16 = (unsigned short*)alloc(NC * 2);
    unsigned short* k16[3], *v16[3];
    for (int r = 0; r < 3; ++r) {
        k16[r] = (unsigned short*)alloc(NC * 2);
        v16[r] = (unsigned short*)alloc(NC * 2);
    }
    unsigned short* ta16 = (unsigned short*)alloc(NC * 2);
    unsigned short* tb16 = (unsigned short*)alloc(NC * 2);
    int* cnt3 = (int*)alloc((size_t)3 * N * 4);
    int* offs3 = (int*)alloc((size_t)3 * N * 4);
    int* fill3 = (int*)alloc((size_t)3 * N * 4);
    int* ss3 = (int*)alloc((size_t)3 * E * 4);
    int* bsum = (int*)alloc(3 * 512 * 4);

    int eb3 = (3 * E + 255) / 256;
    int scanb = (N + SCAN_B - 1) / SCAN_B;

    // fused CSR for all 3 relations
    hipMemsetAsync(cnt3, 0, (size_t)3 * N * sizeof(int), stream);
    count3_kernel<<<eb3, 256, 0, stream>>>(dsts[0], dsts[1], dsts[2], cnt3, E, N);
    scan1_kernel<<<dim3(scanb, 3), SCAN_B, 0, stream>>>(cnt3, offs3, bsum, N);
    scan2_kernel<<<3, 512, 0, stream>>>(bsum, scanb);
    scan3_kernel<<<dim3(scanb, 3), SCAN_B, 0, stream>>>(offs3, bsum, fill3, N);
    scatter3_kernel<<<eb3, 256, 0, stream>>>(srcs[0], dsts[0], srcs[1], dsts[1],
                                             srcs[2], dsts[2], fill3, ss3, E, N);

    // weight prep
    compose_kernel<<<(3 * 16384 + 255) / 256, 256, 0, stream>>>(
        Wk, bk, Wv, bv, att, msg, pri, WkT, WvT, bkC, bvC);
    tcast4_kernel<<<dim3(64, 4), 256, 0, stream>>>(Wq, Wa, WqT, WaT);

    int gblocks = (N + 127) / 128;

    // merged projections (f32 inputs, cast fused into staging)
    OutSpecs8 s8;
    s8.o[0] = {WqT, bq, qa16};
    s8.o[1] = {WkT + 0 * 16384, bkC + 0 * 128, k16[0]};
    s8.o[2] = {WvT + 0 * 16384, bvC + 0 * 128, v16[0]};
    s8.o[3] = {WkT + 2 * 16384, bkC + 2 * 128, k16[2]};
    s8.o[4] = {WvT + 2 * 16384, bvC + 2 * 128, v16[2]};
    s8.o[5] = {WqT + 16384, bq + 128, qb16};
    s8.o[6] = {WkT + 1 * 16384, bkC + 1 * 128, k16[1]};
    s8.o[7] = {WvT + 1 * 16384, bvC + 1 * 128, v16[1]};
    mfma_proj2_kernel<<<2 * gblocks, 256, 0, stream>>>(h_a, h_b, N, s8, gblocks);

    // fused aggregation: 32-lane group per node, both sides in one dispatch
    int bblk = (N + 7) / 8;   // 8 nodes per 256-thread block
    agg_fused_kernel<<<2 * bblk, 256, 0, stream>>>(
        qb16, k16[0], v16[0], offs3 + 0 * N, cnt3 + 0 * N, ss3 + 0 * (size_t)E,
        k16[2], v16[2], offs3 + 2 * N, cnt3 + 2 * N, ss3 + 2 * (size_t)E,
        qa16, k16[1], v16[1], offs3 + 1 * N, cnt3 + 1 * N, ss3 + 1 * (size_t)E,
        tb16, ta16, N, bblk);

    // merged epilogue
    mfma_out2_kernel<<<2 * gblocks, 256, 0, stream>>>(
        ta16, tb16, WaT, ba, h_a, h_b, skip, (float*)d_out, N, gblocks);
}